// Round 15
// baseline (2298.088 us; speedup 1.0000x reference)
//
#include <hip/hip_runtime.h>

typedef _Float16 f16;
typedef __attribute__((ext_vector_type(8))) _Float16 f16x8;
typedef __attribute__((ext_vector_type(4))) _Float16 f16x4;
typedef __attribute__((ext_vector_type(4))) float f32x4;
typedef __attribute__((ext_vector_type(4))) int i32x4;
typedef unsigned long long u64;

#define T_STEPS 784
#define HDIM    512
#define COUT    10
#define NGRP    32                           // groups of 4 CUs, 32 batch rows each
#define XSLOT   32768                        // 2048 chunks x 16B per block-slot

#define WF_BYTES (512 * 1024)
#define XH_OFF   WF_BYTES
#define XH_BYTES (T_STEPS * 1024 * 2)        // f16 xh
#define X_OFF    (XH_OFF + XH_BYTES)
#define X_BYTES  (NGRP * 4 * XSLOT)          // 4 MB: per group {A par0, A par1, B par0, B par1}
#define WS_NEED  ((size_t)(X_OFF + X_BYTES)) // ~6.03 MB

#define MFMA16(a, b, c) __builtin_amdgcn_mfma_f32_16x16x32_f16((a), (b), (c), 0, 0, 0)
#define BAR_LGKM() asm volatile("s_waitcnt lgkmcnt(0)\n\ts_barrier" ::: "memory")

// W_rec f32 -> fp16, frag-major: frag f = ot*16+kk (ot = outcol/16):
//   Wf[f*512 + lane*8 + j] = W_rec[ot*16+(lane&15)][kk*32+(lane>>4)*8+j]
__global__ void cvt_w(const float* __restrict__ W, f16* __restrict__ Wf) {
    const int c  = blockIdx.x * 256 + threadIdx.x;
    const int l  = c & 63;
    const int kk = (c >> 6) & 15;
    const int ot = c >> 10;
    const int row = ot * 16 + (l & 15);
    const int col = kk * 32 + (l >> 4) * 8;
    const float* s = W + row * HDIM + col;
    f16* d = Wf + (size_t)c * 8;
#pragma unroll
    for (int j = 0; j < 8; ++j) d[j] = (f16)s[j];
}

// xh[t][b] = (f16) x[b][perm[t]]
__global__ void permute_x(const float* __restrict__ x, const int* __restrict__ perm,
                          f16* __restrict__ xh) {
    const int i = blockIdx.x * 256 + threadIdx.x;
    const int t = i >> 10, b = i & 1023;
    xh[i] = (f16)x[b * T_STEPS + perm[t]];
}

// zero the exchange region every launch (tags must start at 0 per replay)
__global__ void reset_x(i32x4* __restrict__ X) {
    const int i = blockIdx.x * 256 + threadIdx.x;
    const i32x4 z = {0, 0, 0, 0};
#pragma unroll
    for (int k = 0; k < 4; ++k) X[i + k * 65536] = z;
}

// ---- stage: r10-proven batched 8-chunk poll (parallel retry) + LDS scatter -
#define PUTC(i, V, SXP) *(u64*)((SXP) + dst[i]) = ((u64)(unsigned)(V)[0]) | (((u64)(unsigned)(V)[1]) << 32);
#define POLL8_STAGE(SBASE, TG, SXP)                                          \
    {                                                                        \
        const char* q0 = (SBASE);                                            \
        const char* q1 = (SBASE) + 4096;  const char* q2 = (SBASE) + 8192;   \
        const char* q3 = (SBASE) + 12288; const char* q4 = (SBASE) + 16384;  \
        const char* q5 = (SBASE) + 20480; const char* q6 = (SBASE) + 24576;  \
        const char* q7 = (SBASE) + 28672;                                    \
        i32x4 v0, v1, v2, v3, v4, v5, v6, v7;                                \
        for (;;) {                                                           \
            asm volatile(                                                    \
                "global_load_dwordx4 %0, %8, off sc0 sc1\n\t"               \
                "global_load_dwordx4 %1, %9, off sc0 sc1\n\t"               \
                "global_load_dwordx4 %2, %10, off sc0 sc1\n\t"              \
                "global_load_dwordx4 %3, %11, off sc0 sc1\n\t"              \
                "global_load_dwordx4 %4, %12, off sc0 sc1\n\t"              \
                "global_load_dwordx4 %5, %13, off sc0 sc1\n\t"              \
                "global_load_dwordx4 %6, %14, off sc0 sc1\n\t"              \
                "global_load_dwordx4 %7, %15, off sc0 sc1\n\t"              \
                "s_waitcnt vmcnt(0)"                                         \
                : "=&v"(v0), "=&v"(v1), "=&v"(v2), "=&v"(v3),                \
                  "=&v"(v4), "=&v"(v5), "=&v"(v6), "=&v"(v7)                 \
                : "v"(q0), "v"(q1), "v"(q2), "v"(q3),                        \
                  "v"(q4), "v"(q5), "v"(q6), "v"(q7)                         \
                : "memory");                                                 \
            if (v0[2] == (TG) && v1[2] == (TG) && v2[2] == (TG) &&           \
                v3[2] == (TG) && v4[2] == (TG) && v5[2] == (TG) &&           \
                v6[2] == (TG) && v7[2] == (TG)) break;                       \
            __builtin_amdgcn_s_sleep(1);                                     \
        }                                                                    \
        PUTC(0, v0, SXP) PUTC(1, v1, SXP) PUTC(2, v2, SXP) PUTC(3, v3, SXP)  \
        PUTC(4, v4, SXP) PUTC(5, v5, SXP) PUTC(6, v6, SXP) PUTC(7, v7, SXP)  \
    }

// 16 kk-slices of MFMA for one block (A-frags: LDS kk0..13, regs kk14/15)
#define MFMA_BLK(SXP, AE0, AO0, AE1, AO1)                                    \
    {                                                                        \
        _Pragma("unroll")                                                    \
        for (int kk = 0; kk < 14; ++kk) {                                    \
            const f16x8 bh = *(const f16x8*)((SXP) + kk * 1024 + lane * 16); \
            const f16x8 a0 = *(const f16x8*)(lds + (((w*2+0)*14+kk)*1024) + lane*16); \
            const f16x8 a1 = *(const f16x8*)(lds + (((w*2+1)*14+kk)*1024) + lane*16); \
            if (kk & 1) { AO0 = MFMA16(a0, bh, AO0); AO1 = MFMA16(a1, bh, AO1); } \
            else        { AE0 = MFMA16(a0, bh, AE0); AE1 = MFMA16(a1, bh, AE1); } \
        }                                                                    \
        const f16x8 bh14 = *(const f16x8*)((SXP) + 14 * 1024 + lane * 16);   \
        const f16x8 bh15 = *(const f16x8*)((SXP) + 15 * 1024 + lane * 16);   \
        AE0 = MFMA16(a14_0, bh14, AE0); AE1 = MFMA16(a14_1, bh14, AE1);      \
        AO0 = MFMA16(a15_0, bh15, AO0); AO1 = MFMA16(a15_1, bh15, AO1);      \
    }

// epilogue for one block: inject + relu, pack {h, tag}, 2 x 16B sc0sc1 stores
#define EPI_BLK(XO, XV, AE0, AO0, AE1, AO1, TAG)                             \
    {                                                                        \
        union { f16x4 h; int d[2]; } u0, u1;                                 \
        _Pragma("unroll")                                                    \
        for (int r = 0; r < 4; ++r) {                                        \
            u0.h[r] = (f16)fmaxf(AE0[r] + AO0[r] + (XV) * win0[r], 0.f);     \
            u1.h[r] = (f16)fmaxf(AE1[r] + AO1[r] + (XV) * win1[r], 0.f);     \
        }                                                                    \
        const i32x4 s0 = {u0.d[0], u0.d[1], (TAG), 0};                       \
        const i32x4 s1 = {u1.d[0], u1.d[1], (TAG), 0};                       \
        asm volatile("global_store_dwordx4 %0, %1, off sc0 sc1"              \
                     :: "v"((XO) + wc0), "v"(s0) : "memory");                \
        asm volatile("global_store_dwordx4 %0, %1, off sc0 sc1"              \
                     :: "v"((XO) + wc1), "v"(s1) : "memory");                \
    }

// ---- main: 4-CU groups, 2-block interleave, W in LDS, tag-in-data exchange -
// 128 WGs x 256 thr, 1 WG/CU (144 KB LDS). group g = bid&31 owns 32 batch
// rows as blocks A (rows 0..15) and B (16..31); part p = bid>>5 owns outcols
// [p*128,(p+1)*128); wave w owns otiles p*8+2w, p*8+2w+1.
// Per tick: poll A (data stored a full tick ago -> first-try hit), MFMA A,
// store A; then same for B. Each block's store->poll age = 1 tick, so the
// closed-loop poll overshoot of r10/r14 disappears. All primitives r10-proven.
__global__ __launch_bounds__(256)
void rnn_tag(const float* __restrict__ W_in, const f16* __restrict__ Wf,
             const f16* __restrict__ xh, char* __restrict__ X,
             const float* __restrict__ W_out, const float* __restrict__ b_out,
             float* __restrict__ out)
{
    __shared__ __align__(16) char lds[147456];   // [0,112K): W; [112K,128K): SXA; [128K,144K): SXB
    char* const SXA = lds + 114688;
    char* const SXB = lds + 131072;

    const int tid  = threadIdx.x;
    const int w    = tid >> 6;
    const int lane = tid & 63;
    const int b_   = lane & 15;
    const int lhi  = lane >> 4;
    const int g    = blockIdx.x & 31;
    const int p    = blockIdx.x >> 5;
    const int ot0  = p * 8 + w * 2, ot1 = ot0 + 1;
    const int b0   = g * 32;
    char* const Xg = X + (size_t)g * (4 * XSLOT);   // {A p0, A p1, B p0, B p1}

    // fill W LDS (kk 0..13 for both otiles)
#pragma unroll
    for (int j = 0; j < 2; ++j) {
        const int ot = ot0 + j;
#pragma unroll
        for (int kk = 0; kk < 14; ++kk)
            *(f16x8*)(lds + (((w * 2 + j) * 14 + kk) * 1024) + lane * 16)
                = *(const f16x8*)(Wf + ((size_t)(ot * 16 + kk) * 64 + lane) * 8);
    }
    // kk 14,15 A-frags held in registers (loop-invariant)
    const f16x8 a14_0 = *(const f16x8*)(Wf + ((size_t)(ot0 * 16 + 14) * 64 + lane) * 8);
    const f16x8 a15_0 = *(const f16x8*)(Wf + ((size_t)(ot0 * 16 + 15) * 64 + lane) * 8);
    const f16x8 a14_1 = *(const f16x8*)(Wf + ((size_t)(ot1 * 16 + 14) * 64 + lane) * 8);
    const f16x8 a15_1 = *(const f16x8*)(Wf + ((size_t)(ot1 * 16 + 15) * 64 + lane) * 8);

    float win0[4], win1[4];
#pragma unroll
    for (int r = 0; r < 4; ++r) {
        win0[r] = W_in[ot0 * 16 + lhi * 4 + r];
        win1[r] = W_in[ot1 * 16 + lhi * 4 + r];
    }

    // stage destinations (chunk c -> B-frag byte offset; layout proven r6-r14)
    int dst[8];
#pragma unroll
    for (int i = 0; i < 8; ++i) {
        const int c = tid + 256 * i;
        const int ot = c >> 6, lh = (c >> 4) & 3, bb = c & 15;
        dst[i] = (ot >> 1) * 1024 + ((ot & 1) * 2 + (lh >> 1)) * 256 + bb * 16 + (lh & 1) * 8;
    }
    // writer chunk byte offsets (within a block-slot)
    const int wc0 = (ot0 * 64 + lhi * 16 + b_) * 16;
    const int wc1 = (ot1 * 64 + lhi * 16 + b_) * 16;

    __syncthreads();   // W LDS ready

#pragma unroll 1
    for (int t = 0; t < T_STEPS; ++t) {
        const float xvA = (float)xh[t * 1024 + b0 + b_];
        const float xvB = (float)xh[t * 1024 + b0 + 16 + b_];
        const int par_r = (t - 1) & 1;     // read-slot parity
        const int par_w = t & 1;           // write-slot parity

        f32x4 ae0 = {0.f, 0.f, 0.f, 0.f}, ao0 = {0.f, 0.f, 0.f, 0.f};
        f32x4 ae1 = {0.f, 0.f, 0.f, 0.f}, ao1 = {0.f, 0.f, 0.f, 0.f};

        // ---- block A ----
        if (t > 0) {
            POLL8_STAGE(Xg + par_r * XSLOT + tid * 16, t, SXA)
            BAR_LGKM();
            MFMA_BLK(SXA, ae0, ao0, ae1, ao1)
        }
        EPI_BLK(Xg + par_w * XSLOT, xvA, ae0, ao0, ae1, ao1, t + 1)

        // ---- block B ----
        ae0 = (f32x4){0.f, 0.f, 0.f, 0.f}; ao0 = (f32x4){0.f, 0.f, 0.f, 0.f};
        ae1 = (f32x4){0.f, 0.f, 0.f, 0.f}; ao1 = (f32x4){0.f, 0.f, 0.f, 0.f};
        if (t > 0) {
            POLL8_STAGE(Xg + (2 + par_r) * XSLOT + tid * 16, t, SXB)
            BAR_LGKM();
            MFMA_BLK(SXB, ae0, ao0, ae1, ao1)
        }
        EPI_BLK(Xg + (2 + par_w) * XSLOT, xvB, ae0, ao0, ae1, ao1, t + 1)
        // no trailing barrier: SXA/SXB reuse is gated transitively by the
        // tag polls (stage-X(t+1) requires every wave's tag-t+1 store, which
        // follows its MFMA-X(t) read of SX)
    }

    // ---- projection by part-0 WGs: out[b,c] = h_last . W_out[c,:] + b_out[c]
    if (p == 0) {
        const int parf = (T_STEPS - 1) & 1;
#pragma unroll 1
        for (int blk = 0; blk < 2; ++blk) {
            POLL8_STAGE(Xg + (2 * blk + parf) * XSLOT + tid * 16, T_STEPS, SXA)
            BAR_LGKM();
            if (tid < 16 * COUT) {
                const int bb = tid / COUT, c = tid % COUT;
                float s_ = b_out[c];
                const float* wo = W_out + c * HDIM;
#pragma unroll 4
                for (int o0 = 0; o0 < HDIM; o0 += 8) {
                    const int off = (o0 >> 5) * 1024 + ((((o0 >> 3) & 3) << 4) | bb) * 16;
                    f16x8 hvv = *(const f16x8*)(SXA + off);
#pragma unroll
                    for (int jj = 0; jj < 8; ++jj)
                        s_ += (float)hvv[jj] * wo[o0 + jj];
                }
                out[(b0 + blk * 16 + bb) * COUT + c] = s_;
            }
            __syncthreads();   // SXA reused by next blk
        }
    }
}

// ---- fallback (round-6 proven kernel, f16 xt) ------------------------------
__global__ __launch_bounds__(512, 2)
void rnn_fb(const float* __restrict__ W_in, const f16* __restrict__ Wf,
            const float* __restrict__ W_out, const float* __restrict__ b_out,
            const f16* __restrict__ xt, float* __restrict__ out)
{
    __shared__ __align__(16) char hb[32768];
    const int tid  = threadIdx.x;
    const int w    = tid >> 6;
    const int lane = tid & 63;
    const int b    = lane & 15;
    const int lhi  = lane >> 4;
    const int b0   = blockIdx.x * 16;

    for (int i = tid; i < 4096; i += 512) ((int*)hb)[i] = 0;

    const f16* wb = Wf + (size_t)w * 64 * 512 + lane * 8;
#define LDW(kk, n) (*(const f16x8*)(wb + ((n) * 16 + (kk)) * 512))

    f16x4 win[4];
#pragma unroll
    for (int n = 0; n < 4; ++n)
#pragma unroll
        for (int r = 0; r < 4; ++r)
            win[n][r] = (f16)W_in[w * 64 + n * 16 + lhi * 4 + r];

    char* const rb = hb + lane * 16;
    int wa[4];
#pragma unroll
    for (int n = 0; n < 4; ++n)
        wa[n] = (2 * w + (n >> 1)) * 1024
              + (((((n & 1) * 2 + (lhi >> 1)) << 4) | b) * 16)
              + (lhi & 1) * 8;

    __syncthreads();

    f16x8 r0[4], r1[4], r2[4], r3[4];
#pragma unroll
    for (int n = 0; n < 4; ++n) r0[n] = LDW(0, n);
#pragma unroll
    for (int n = 0; n < 4; ++n) r1[n] = LDW(1, n);
#pragma unroll
    for (int n = 0; n < 4; ++n) r2[n] = LDW(2, n);
#pragma unroll
    for (int n = 0; n < 4; ++n) r3[n] = LDW(3, n);

#define STEP_KK(kk, RING, nxt)                                      \
    {                                                               \
        const f16x8 bh = *(const f16x8*)(rp + (kk) * 1024);         \
        acc0 = MFMA16(RING[0], bh, acc0);                           \
        acc1 = MFMA16(RING[1], bh, acc1);                           \
        acc2 = MFMA16(RING[2], bh, acc2);                           \
        acc3 = MFMA16(RING[3], bh, acc3);                           \
        RING[0] = LDW(nxt, 0); RING[1] = LDW(nxt, 1);               \
        RING[2] = LDW(nxt, 2); RING[3] = LDW(nxt, 3);               \
    }

    int cur = 0;
#pragma unroll 1
    for (int t = 0; t < T_STEPS; ++t) {
        const float xv = (float)xt[t * 1024 + b0 + b];
        const char* rp = rb + cur;
        char* wq = hb + (cur ^ 16384);

        f32x4 acc0 = {0.f, 0.f, 0.f, 0.f};
        f32x4 acc1 = {0.f, 0.f, 0.f, 0.f};
        f32x4 acc2 = {0.f, 0.f, 0.f, 0.f};
        f32x4 acc3 = {0.f, 0.f, 0.f, 0.f};

        STEP_KK(0,  r0, 4)   STEP_KK(1,  r1, 5)
        STEP_KK(2,  r2, 6)   STEP_KK(3,  r3, 7)
        STEP_KK(4,  r0, 8)   STEP_KK(5,  r1, 9)
        STEP_KK(6,  r2, 10)  STEP_KK(7,  r3, 11)
        STEP_KK(8,  r0, 12)  STEP_KK(9,  r1, 13)
        STEP_KK(10, r2, 14)  STEP_KK(11, r3, 15)
        STEP_KK(12, r0, 0)   STEP_KK(13, r1, 1)
        STEP_KK(14, r2, 2)   STEP_KK(15, r3, 3)

        {
            f16x4 hv;
            float v;
#define EPI(n, ACC)                                                  \
            v = ACC[0] + xv * (float)win[n][0]; hv[0] = (f16)fmaxf(v, 0.f); \
            v = ACC[1] + xv * (float)win[n][1]; hv[1] = (f16)fmaxf(v, 0.f); \
            v = ACC[2] + xv * (float)win[n][2]; hv[2] = (f16)fmaxf(v, 0.f); \
            v = ACC[3] + xv * (float)win[n][3]; hv[3] = (f16)fmaxf(v, 0.f); \
            *(f16x4*)(wq + wa[n]) = hv;
            EPI(0, acc0) EPI(1, acc1) EPI(2, acc2) EPI(3, acc3)
#undef EPI
        }

        asm volatile("s_waitcnt lgkmcnt(0)\n\ts_barrier" ::: "memory");
        cur ^= 16384;
    }

    if (tid < 16 * COUT) {
        const int bb = tid / COUT, c = tid % COUT;
        const char* hr = hb + cur;
        float s_ = b_out[c];
        const float* wo = W_out + c * HDIM;
#pragma unroll 4
        for (int o0 = 0; o0 < HDIM; o0 += 8) {
            const int off = (o0 >> 5) * 1024 + (((((o0 >> 3) & 3) << 4) | bb) * 16);
            f16x8 hv = *(const f16x8*)(hr + off);
#pragma unroll
            for (int jj = 0; jj < 8; ++jj)
                s_ += (float)hv[jj] * wo[o0 + jj];
        }
        out[(b0 + bb) * COUT + c] = s_;
    }
}

extern "C" void kernel_launch(void* const* d_in, const int* in_sizes, int n_in,
                              void* d_out, int out_size, void* d_ws, size_t ws_size,
                              hipStream_t stream)
{
    (void)in_sizes; (void)n_in; (void)out_size;
    const float* x     = (const float*)d_in[0];
    const float* W_in  = (const float*)d_in[1];
    const float* W_rec = (const float*)d_in[2];
    const float* W_out = (const float*)d_in[3];
    const float* b_out = (const float*)d_in[4];
    const int*   perm  = (const int*)d_in[5];
    float* out = (float*)d_out;

    f16*  Wf  = (f16*)d_ws;
    f16*  xhp = (f16*)((char*)d_ws + XH_OFF);
    char* X   = (char*)d_ws + X_OFF;

    cvt_w<<<dim3(128), dim3(256), 0, stream>>>(W_rec, Wf);
    permute_x<<<dim3(T_STEPS * 1024 / 256), dim3(256), 0, stream>>>(x, perm, xhp);

    if (ws_size >= WS_NEED) {
        reset_x<<<dim3(256), dim3(256), 0, stream>>>((i32x4*)X);
        rnn_tag<<<dim3(128), dim3(256), 0, stream>>>(W_in, Wf, xhp, X,
                                                     W_out, b_out, out);
    } else {
        rnn_fb<<<dim3(64), dim3(512), 0, stream>>>(W_in, Wf, W_out, b_out, xhp, out);
    }
}

// Round 16
// 1205.573 us; speedup vs baseline: 1.9062x; 1.9062x over previous
//
#include <hip/hip_runtime.h>

typedef _Float16 f16;
typedef __attribute__((ext_vector_type(8))) _Float16 f16x8;
typedef __attribute__((ext_vector_type(4))) _Float16 f16x4;
typedef __attribute__((ext_vector_type(4))) float f32x4;

#define T_STEPS 784
#define HDIM    512
#define COUT    10

#define XH_OFF   (512 * 1024)
#define WS_NEED  ((size_t)(XH_OFF + T_STEPS * 1024 * 2))

#define MFMA16(a, b, c) __builtin_amdgcn_mfma_f32_16x16x32_f16((a), (b), (c), 0, 0, 0)
#define BAR_LGKM() asm volatile("s_waitcnt lgkmcnt(0)\n\ts_barrier" ::: "memory")

// W_rec f32 -> fp16, frag-major: frag f = (w*4+n)*16+kk:
//   Wf[f*512 + lane*8 + j] = W_rec[w*64+n*16+(lane&15)][kk*32+(lane>>4)*8+j]
__global__ void cvt_w(const float* __restrict__ W, f16* __restrict__ Wf) {
    const int c  = blockIdx.x * 256 + threadIdx.x;
    const int l  = c & 63;
    const int kk = (c >> 6) & 15;
    const int n  = (c >> 10) & 3;
    const int w  = c >> 12;
    const int row = w * 64 + n * 16 + (l & 15);
    const int col = kk * 32 + (l >> 4) * 8;
    const float* s = W + row * HDIM + col;
    f16* d = Wf + (size_t)c * 8;
#pragma unroll
    for (int j = 0; j < 8; ++j) d[j] = (f16)s[j];
}

// xh[t][b] = (f16) x[b][perm[t]]
__global__ void permute_x(const float* __restrict__ x, const int* __restrict__ perm,
                          f16* __restrict__ xh) {
    const int i = blockIdx.x * 256 + threadIdx.x;
    const int t = i >> 10, b = i & 1023;
    xh[i] = (f16)x[b * T_STEPS + perm[t]];
}

// ---- main: in-CU recurrence, NO cross-WG sync -------------------------------
// 64 WGs x 512 thr (8 waves, 2/SIMD). WG owns 16 batch rows, all 512 outcols;
// wave w owns outcols [w*64, w*64+64) (otiles n=0..3).
// W: kk 0..3 A-frags cached in LDS (128 KB, filled once); kk 4..15 streamed
// from L2 per step through a 4-deep register ring, with PER-WG ROTATION of
// the streamed order (de-phases the 8 WGs/XCD sweeping the same addresses).
// h: single 16 KB LDS buffer (frag-major, conflict-free); two lgkm barriers
// per step (read-phase / write-phase). No exchange buffers, no tags.
__global__ __launch_bounds__(512, 2)
void rnn_l2(const float* __restrict__ W_in, const f16* __restrict__ Wf,
            const f16* __restrict__ xh, const float* __restrict__ W_out,
            const float* __restrict__ b_out, float* __restrict__ out)
{
    __shared__ __align__(16) char lds[147456];   // [0,128K): W cache; [128K,144K): h
    char* const HB = lds + 131072;

    const int tid  = threadIdx.x;
    const int w    = tid >> 6;
    const int lane = tid & 63;
    const int b_   = lane & 15;
    const int lhi  = lane >> 4;
    const int b0   = blockIdx.x * 16;

    const f16* wb = Wf + (size_t)w * 32768 + lane * 8;
#define LDW(kk, n) (*(const f16x8*)(wb + ((n) * 16 + (kk)) * 512))

    // fill W cache: kk 0..3 for this wave's 4 otiles
#pragma unroll
    for (int n = 0; n < 4; ++n)
#pragma unroll
        for (int ck = 0; ck < 4; ++ck)
            *(f16x8*)(lds + (((w * 4 + n) * 4 + ck) * 1024) + lane * 16) = LDW(ck, n);

    // zero h buffer (h0 = 0)
    for (int i = tid; i < 4096; i += 512) ((int*)HB)[i] = 0;

    f16x4 win[4];
#pragma unroll
    for (int n = 0; n < 4; ++n)
#pragma unroll
        for (int r = 0; r < 4; ++r)
            win[n][r] = (f16)W_in[w * 64 + n * 16 + lhi * 4 + r];

    // h LDS addresses (frag-major, proven r6): read rb + kk*1024; write wa[n]
    char* const rb = HB + lane * 16;
    int wa[4];
#pragma unroll
    for (int n = 0; n < 4; ++n)
        wa[n] = (2 * w + (n >> 1)) * 1024
              + (((((n & 1) * 2 + (lhi >> 1)) << 4) | b_) * 16)
              + (lhi & 1) * 8;

    // per-WG rotation of streamed slice order (kk 4..15)
    const int rot = (int)((blockIdx.x * 7u) % 12u);
    int ks[12];
#pragma unroll
    for (int i = 0; i < 12; ++i) {
        int v = i + rot; if (v >= 12) v -= 12;
        ks[i] = 4 + v;
    }

    __syncthreads();   // W cache + h zero ready

    // preload ring with first 4 streamed slices
    f16x8 r0[4], r1[4], r2[4], r3[4];
#pragma unroll
    for (int n = 0; n < 4; ++n) r0[n] = LDW(ks[0], n);
#pragma unroll
    for (int n = 0; n < 4; ++n) r1[n] = LDW(ks[1], n);
#pragma unroll
    for (int n = 0; n < 4; ++n) r2[n] = LDW(ks[2], n);
#pragma unroll
    for (int n = 0; n < 4; ++n) r3[n] = LDW(ks[3], n);

#define STEP_KK(kki, RING, nxtk)                                    \
    {                                                               \
        const f16x8 bh = *(const f16x8*)(rb + (kki) * 1024);        \
        acc0 = MFMA16(RING[0], bh, acc0);                           \
        acc1 = MFMA16(RING[1], bh, acc1);                           \
        acc2 = MFMA16(RING[2], bh, acc2);                           \
        acc3 = MFMA16(RING[3], bh, acc3);                           \
        RING[0] = LDW(nxtk, 0); RING[1] = LDW(nxtk, 1);             \
        RING[2] = LDW(nxtk, 2); RING[3] = LDW(nxtk, 3);             \
    }
#define CACHED_KK(ck)                                               \
    {                                                               \
        const f16x8 bh = *(const f16x8*)(rb + (ck) * 1024);         \
        const f16x8 a0 = *(const f16x8*)(lds + (((w * 4 + 0) * 4 + (ck)) * 1024) + lane * 16); \
        const f16x8 a1 = *(const f16x8*)(lds + (((w * 4 + 1) * 4 + (ck)) * 1024) + lane * 16); \
        const f16x8 a2 = *(const f16x8*)(lds + (((w * 4 + 2) * 4 + (ck)) * 1024) + lane * 16); \
        const f16x8 a3 = *(const f16x8*)(lds + (((w * 4 + 3) * 4 + (ck)) * 1024) + lane * 16); \
        acc0 = MFMA16(a0, bh, acc0);                                \
        acc1 = MFMA16(a1, bh, acc1);                                \
        acc2 = MFMA16(a2, bh, acc2);                                \
        acc3 = MFMA16(a3, bh, acc3);                                \
    }

#pragma unroll 1
    for (int t = 0; t < T_STEPS; ++t) {
        const float xv = (float)xh[t * 1024 + b0 + b_];

        f32x4 acc0 = {0.f, 0.f, 0.f, 0.f};
        f32x4 acc1 = {0.f, 0.f, 0.f, 0.f};
        f32x4 acc2 = {0.f, 0.f, 0.f, 0.f};
        f32x4 acc3 = {0.f, 0.f, 0.f, 0.f};

        // cached slices first: compute runs while the streamed ring flies
        CACHED_KK(0) CACHED_KK(1) CACHED_KK(2) CACHED_KK(3)
        // streamed slices (rotated order); tail reloads prefetch next step
        STEP_KK(ks[0], r0, ks[4])   STEP_KK(ks[1], r1, ks[5])
        STEP_KK(ks[2], r2, ks[6])   STEP_KK(ks[3], r3, ks[7])
        STEP_KK(ks[4], r0, ks[8])   STEP_KK(ks[5], r1, ks[9])
        STEP_KK(ks[6], r2, ks[10])  STEP_KK(ks[7], r3, ks[11])
        STEP_KK(ks[8], r0, ks[0])   STEP_KK(ks[9], r1, ks[1])
        STEP_KK(ks[10], r2, ks[2])  STEP_KK(ks[11], r3, ks[3])

        BAR_LGKM();   // all waves' h reads complete (lgkm only; ring stays in flight)

        // epilogue: inject + relu, 4 x 8B stores into the single h buffer
        {
            f16x4 hv;
            float v;
#define EPI(n, ACC)                                                  \
            v = ACC[0] + xv * (float)win[n][0]; hv[0] = (f16)fmaxf(v, 0.f); \
            v = ACC[1] + xv * (float)win[n][1]; hv[1] = (f16)fmaxf(v, 0.f); \
            v = ACC[2] + xv * (float)win[n][2]; hv[2] = (f16)fmaxf(v, 0.f); \
            v = ACC[3] + xv * (float)win[n][3]; hv[3] = (f16)fmaxf(v, 0.f); \
            *(f16x4*)(HB + wa[n]) = hv;
            EPI(0, acc0) EPI(1, acc1) EPI(2, acc2) EPI(3, acc3)
#undef EPI
        }

        BAR_LGKM();   // h(t+1) visible before next step's reads
    }

    // projection: out[b,c] = h_last[b,:] . W_out[c,:] + b_out[c]
    if (tid < 16 * COUT) {
        const int bb = tid / COUT, c = tid % COUT;
        float s_ = b_out[c];
        const float* wo = W_out + c * HDIM;
#pragma unroll 4
        for (int o0 = 0; o0 < HDIM; o0 += 8) {
            const int off = (o0 >> 5) * 1024 + (((((o0 >> 3) & 3) << 4) | bb) * 16);
            f16x8 hv = *(const f16x8*)(HB + off);
#pragma unroll
            for (int jj = 0; jj < 8; ++jj)
                s_ += (float)hv[jj] * wo[o0 + jj];
        }
        out[(b0 + bb) * COUT + c] = s_;
    }
}

extern "C" void kernel_launch(void* const* d_in, const int* in_sizes, int n_in,
                              void* d_out, int out_size, void* d_ws, size_t ws_size,
                              hipStream_t stream)
{
    (void)in_sizes; (void)n_in; (void)out_size; (void)ws_size;
    const float* x     = (const float*)d_in[0];
    const float* W_in  = (const float*)d_in[1];
    const float* W_rec = (const float*)d_in[2];
    const float* W_out = (const float*)d_in[3];
    const float* b_out = (const float*)d_in[4];
    const int*   perm  = (const int*)d_in[5];
    float* out = (float*)d_out;

    f16* Wf  = (f16*)d_ws;                           // 512 KB
    f16* xhp = (f16*)((char*)d_ws + XH_OFF);         // 1.6 MB

    cvt_w<<<dim3(128), dim3(256), 0, stream>>>(W_rec, Wf);
    permute_x<<<dim3(T_STEPS * 1024 / 256), dim3(256), 0, stream>>>(x, perm, xhp);
    rnn_l2<<<dim3(64), dim3(512), 0, stream>>>(W_in, Wf, xhp, W_out, b_out, out);
}